// Round 7
// baseline (351.229 us; speedup 1.0000x reference)
//
#include <hip/hip_runtime.h>
#include <math.h>

constexpr int NB = 64;
constexpr int NS = 1024;
constexpr int NH = 1024;
constexpr int NE = 1024;
constexpr int NV = 50257;
constexpr int NK2 = 2048;

typedef __bf16 bf16_8 __attribute__((ext_vector_type(8)));
typedef float  f32x4  __attribute__((ext_vector_type(4)));

// ---------------- build A_g = [emb[x] | h] (64 x 2048) in bf16
__global__ __launch_bounds__(256) void k_cvtAg(const int* __restrict__ x,
    const float* __restrict__ h, const float* __restrict__ emb,
    __bf16* __restrict__ Ag) {
  int t = blockIdx.x * 256 + threadIdx.x;  // 0..131071
  int b = t >> 11, k = t & 2047;
  float v = (k < NE) ? emb[(size_t)x[b] * NE + k] : h[b * NH + (k - NE)];
  Ag[t] = (__bf16)v;
}

// ---------------- gates GEMM via bf16 MFMA (W streamed, no LDS staging)
__global__ __launch_bounds__(256) void k_gates_mfma(const __bf16* __restrict__ Ag,
    const float* __restrict__ Wih, const float* __restrict__ bih,
    const float* __restrict__ Whh, const float* __restrict__ bhh,
    float* __restrict__ gates) {
  __shared__ f32x4 red[4][4][64];
  int lane = threadIdx.x & 63;
  int wave = threadIdx.x >> 6;
  int col  = lane & 15;
  int grp  = lane >> 4;
  int j    = blockIdx.x * 16 + col;

  const float* Wsel = (wave < 2) ? Wih : Whh;
  const float*  wp  = Wsel + (size_t)j * 1024 + (wave & 1) * 512 + grp * 8;
  const __bf16* ap  = Ag + wave * 512 + grp * 8;

  f32x4 acc[4] = {};
#pragma unroll 4
  for (int ks = 0; ks < 16; ++ks) {
    int kb = ks * 32;
    float4 b0 = *(const float4*)(wp + kb);
    float4 b1 = *(const float4*)(wp + kb + 4);
    bf16_8 bf;
    bf[0] = (__bf16)b0.x; bf[1] = (__bf16)b0.y;
    bf[2] = (__bf16)b0.z; bf[3] = (__bf16)b0.w;
    bf[4] = (__bf16)b1.x; bf[5] = (__bf16)b1.y;
    bf[6] = (__bf16)b1.z; bf[7] = (__bf16)b1.w;
#pragma unroll
    for (int m = 0; m < 4; ++m) {
      bf16_8 a = *(const bf16_8*)(ap + (m * 16 + col) * NK2 + kb);
      acc[m] = __builtin_amdgcn_mfma_f32_16x16x32_bf16(a, bf, acc[m], 0, 0, 0);
    }
  }
#pragma unroll
  for (int m = 0; m < 4; ++m) red[wave][m][lane] = acc[m];
  __syncthreads();
  f32x4 s = red[0][wave][lane];
#pragma unroll
  for (int wv = 1; wv < 4; ++wv) s += red[wv][wave][lane];
  float bias = bih[j] + bhh[j];
  int b = wave * 16 + grp * 4;
#pragma unroll
  for (int r = 0; r < 4; ++r)
    gates[(b + r) * 4096 + j] = s[r] + bias;
}

// ---------------- LSTM cell elementwise (also emits bf16 h_new into A[:,1024:])
__global__ __launch_bounds__(256) void k_lstm(const float* __restrict__ gates,
    const float* __restrict__ c, float* __restrict__ hc_out,
    __bf16* __restrict__ A_bf) {
  int t = blockIdx.x * 256 + threadIdx.x;  // 0..NB*NH
  int b = t >> 10, hh = t & 1023;
  float ig = gates[b * 4096 + hh];
  float fg = gates[b * 4096 + 1024 + hh];
  float gg = gates[b * 4096 + 2048 + hh];
  float og = gates[b * 4096 + 3072 + hh];
  float i_ = 1.f / (1.f + expf(-ig));
  float f_ = 1.f / (1.f + expf(-fg));
  float g_ = tanhf(gg);
  float o_ = 1.f / (1.f + expf(-og));
  float cn = f_ * c[t] + i_ * g_;
  float hn = o_ * tanhf(cn);
  hc_out[t] = hn;                 // h_new
  hc_out[NB * NH + t] = cn;       // c_new
  A_bf[b * NK2 + 1024 + hh] = (__bf16)hn;
}

// ---------------- t = h_new @ W_bilin
__global__ __launch_bounds__(256) void k_bilin(const float* __restrict__ hnew,
    const float* __restrict__ Wb, float* __restrict__ t_out) {
  int b = blockIdx.x >> 2;
  int k = ((blockIdx.x & 3) << 8) + threadIdx.x;
  const float* hb = hnew + b * NH;
  float acc = 0.f;
#pragma unroll 8
  for (int hh = 0; hh < NH; ++hh)
    acc += hb[hh] * Wb[hh * NH + k];
  t_out[b * NH + k] = acc;
}

// ---------------- barrier-free flash attention: one WAVE per (b, 8-row strip).
// 8192 waves (~32/CU) for deep memory-level parallelism. No LDS, no barriers.
// Masked rows (s>=len) get value 0 (not -inf) and DO accumulate, per reference.
__global__ __launch_bounds__(256) void k_attn(const float* __restrict__ t_in,
    const float* __restrict__ enc, const int* __restrict__ length,
    float* __restrict__ ctxp, float* __restrict__ ml) {
  int b     = blockIdx.x >> 5;                                   // 64
  int strip = ((blockIdx.x & 31) << 2) + (threadIdx.x >> 6);     // 0..127
  int lane  = threadIdx.x & 63;
  int len   = length[b];
  int s0    = strip * 8;

  const float4* tp4 = (const float4*)(t_in + b * NH);
  float4 tv[4];
#pragma unroll
  for (int i = 0; i < 4; ++i) tv[i] = tp4[i * 64 + lane];

  const float4* ep4 = (const float4*)(enc + ((size_t)b * NS + s0) * NH);

  float m_run = -1e30f, l_run = 0.f;
  f32x4 acc[4] = {};

#pragma unroll 2
  for (int r = 0; r < 8; ++r) {
    float4 e[4];
#pragma unroll
    for (int i = 0; i < 4; ++i) e[i] = ep4[r * 256 + i * 64 + lane];
    float d = 0.f;
#pragma unroll
    for (int i = 0; i < 4; ++i)
      d += tv[i].x * e[i].x + tv[i].y * e[i].y + tv[i].z * e[i].z + tv[i].w * e[i].w;
#pragma unroll
    for (int off = 32; off; off >>= 1) d += __shfl_xor(d, off);
    float v = (s0 + r < len) ? d : 0.f;
    float m_new = fmaxf(m_run, v);
    float f = expf(m_run - m_new);     // first iter: expf(-inf)=0, clean
    float w = expf(v - m_new);
    l_run = l_run * f + w;
#pragma unroll
    for (int i = 0; i < 4; ++i) {
      acc[i][0] = acc[i][0] * f + w * e[i].x;
      acc[i][1] = acc[i][1] * f + w * e[i].y;
      acc[i][2] = acc[i][2] * f + w * e[i].z;
      acc[i][3] = acc[i][3] * f + w * e[i].w;
    }
    m_run = m_new;
  }

  int idx = b * 128 + strip;
  float* P = ctxp + (size_t)idx * 1024;
#pragma unroll
  for (int i = 0; i < 4; ++i)
    *(f32x4*)(P + (i * 64 + lane) * 4) = acc[i];
  if (lane == 0) {
    ml[idx * 2]     = m_run;
    ml[idx * 2 + 1] = l_run;
  }
}

// ---------------- combine 128 strip partials -> context, emit bf16 into A[:,0:1024]
__global__ __launch_bounds__(256) void k_attn_combine(const float* __restrict__ ctxp,
    const float* __restrict__ ml, __bf16* __restrict__ A_bf) {
  int b = blockIdx.x;
  int tid = threadIdx.x;
  float M = -1e30f;
#pragma unroll 8
  for (int c = 0; c < 128; ++c) M = fmaxf(M, ml[(b * 128 + c) * 2]);
  float Z = 0.f;
  f32x4 num = {0.f, 0.f, 0.f, 0.f};
#pragma unroll 4
  for (int c = 0; c < 128; ++c) {
    float e = expf(ml[(b * 128 + c) * 2] - M);
    Z += e * ml[(b * 128 + c) * 2 + 1];
    f32x4 p = *(const f32x4*)(ctxp + ((size_t)(b * 128 + c)) * 1024 + tid * 4);
    num += e * p;
  }
  float inv = 1.f / Z;
  __bf16* dst = A_bf + b * NK2 + tid * 4;
#pragma unroll
  for (int i = 0; i < 4; ++i) dst[i] = (__bf16)(num[i] * inv);
}

// ---------------- out = A @ W_out^T + b_out via bf16 MFMA.
// 16 v-cols per wave, 4 waves/block, grid 786 (~12 waves/CU). Software
// pipeline: prefetch W(k+1) and A(k+1) into regs before cvt+MFMA of step k.
__global__ __launch_bounds__(256) void k_out_mfma(const __bf16* __restrict__ A,
    const float* __restrict__ Wout, const float* __restrict__ bout,
    float* __restrict__ out) {
  int lane = threadIdx.x & 63;
  int wave = threadIdx.x >> 6;
  int col  = lane & 15;
  int grp  = lane >> 4;
  int vrow = blockIdx.x * 64 + wave * 16 + col;
  int vcl  = vrow < NV ? vrow : NV - 1;

  const float*  wp = Wout + (size_t)vcl * NK2 + grp * 8;
  const __bf16* ap = A + grp * 8;

  f32x4 acc[4] = {};

  // prologue: k-step 0 in regs
  float4 w0 = *(const float4*)(wp);
  float4 w1 = *(const float4*)(wp + 4);
  bf16_8 a[4];
#pragma unroll
  for (int m = 0; m < 4; ++m)
    a[m] = *(const bf16_8*)(ap + (size_t)(m * 16 + col) * NK2);

#pragma unroll 2
  for (int ks = 0; ks < 63; ++ks) {
    int kb = (ks + 1) * 32;
    // issue next-step loads FIRST (hide under current cvt+MFMA)
    float4 nw0 = *(const float4*)(wp + kb);
    float4 nw1 = *(const float4*)(wp + kb + 4);
    bf16_8 na[4];
#pragma unroll
    for (int m = 0; m < 4; ++m)
      na[m] = *(const bf16_8*)(ap + (size_t)(m * 16 + col) * NK2 + kb);

    bf16_8 bf;
    bf[0] = (__bf16)w0.x; bf[1] = (__bf16)w0.y;
    bf[2] = (__bf16)w0.z; bf[3] = (__bf16)w0.w;
    bf[4] = (__bf16)w1.x; bf[5] = (__bf16)w1.y;
    bf[6] = (__bf16)w1.z; bf[7] = (__bf16)w1.w;
#pragma unroll
    for (int m = 0; m < 4; ++m)
      acc[m] = __builtin_amdgcn_mfma_f32_16x16x32_bf16(a[m], bf, acc[m], 0, 0, 0);

    w0 = nw0; w1 = nw1;
#pragma unroll
    for (int m = 0; m < 4; ++m) a[m] = na[m];
  }
  // epilogue: last k-step
  {
    bf16_8 bf;
    bf[0] = (__bf16)w0.x; bf[1] = (__bf16)w0.y;
    bf[2] = (__bf16)w0.z; bf[3] = (__bf16)w0.w;
    bf[4] = (__bf16)w1.x; bf[5] = (__bf16)w1.y;
    bf[6] = (__bf16)w1.z; bf[7] = (__bf16)w1.w;
#pragma unroll
    for (int m = 0; m < 4; ++m)
      acc[m] = __builtin_amdgcn_mfma_f32_16x16x32_bf16(a[m], bf, acc[m], 0, 0, 0);
  }

  if (vrow < NV) {
    float bb = bout[vrow];
    int mrow = grp * 4;  // D row = (lane>>4)*4 + reg
#pragma unroll
    for (int m = 0; m < 4; ++m)
#pragma unroll
      for (int r = 0; r < 4; ++r)
        out[(size_t)(m * 16 + mrow + r) * NV + vrow] = acc[m][r] + bb;
  }
}

extern "C" void kernel_launch(void* const* d_in, const int* in_sizes, int n_in,
                              void* d_out, int out_size, void* d_ws, size_t ws_size,
                              hipStream_t stream) {
  const int*   x      = (const int*)d_in[0];
  const float* h      = (const float*)d_in[1];
  const float* c      = (const float*)d_in[2];
  const float* enc    = (const float*)d_in[3];
  const int*   length = (const int*)d_in[4];
  const float* emb    = (const float*)d_in[5];
  const float* Wih    = (const float*)d_in[6];
  const float* bih    = (const float*)d_in[7];
  const float* Whh    = (const float*)d_in[8];
  const float* bhh    = (const float*)d_in[9];
  const float* Wb     = (const float*)d_in[10];
  const float* Wout   = (const float*)d_in[11];
  const float* bout   = (const float*)d_in[12];

  float* out = (float*)d_out;
  float* hn  = out + (size_t)NB * NV;          // h_new region of d_out
  // c_new region = hn + NB*NH (written by k_lstm)

  float* ws      = (float*)d_ws;
  float* gates   = ws;                               // NB*4H f32
  float* t_ws    = gates + NB * 4 * NH;              // NB*NH f32
  float* ctxp    = t_ws + NB * NH;                   // 128*NB*1024 f32 (33.5MB)
  float* ml      = ctxp + 128 * (size_t)NB * 1024;   // NB*128*2 f32
  __bf16* A_bf   = (__bf16*)(ml + NB * 256);         // NB*NK2 bf16
  __bf16* Ag_bf  = A_bf + NB * NK2;                  // NB*NK2 bf16

  k_cvtAg<<<NB * NK2 / 256, 256, 0, stream>>>(x, h, emb, Ag_bf);
  k_gates_mfma<<<4096 / 16, 256, 0, stream>>>(Ag_bf, Wih, bih, Whh, bhh, gates);
  k_lstm<<<NB * NH / 256, 256, 0, stream>>>(gates, c, hn, A_bf);
  k_bilin<<<NB * 4, 256, 0, stream>>>(hn, Wb, t_ws);
  k_attn<<<NB * 32, 256, 0, stream>>>(t_ws, enc, length, ctxp, ml);
  k_attn_combine<<<NB, 256, 0, stream>>>(ctxp, ml, A_bf);
  k_out_mfma<<<(NV + 63) / 64, 256, 0, stream>>>(A_bf, Wout, bout, out);
}

// Round 9
// 269.658 us; speedup vs baseline: 1.3025x; 1.3025x over previous
//
#include <hip/hip_runtime.h>
#include <math.h>

constexpr int NB = 64;
constexpr int NS = 1024;
constexpr int NH = 1024;
constexpr int NE = 1024;
constexpr int NV = 50257;
constexpr int NK2 = 2048;

typedef __bf16 bf16_8 __attribute__((ext_vector_type(8)));
typedef float  f32x4  __attribute__((ext_vector_type(4)));

// nontemporal 16B load via native vector type (HIP float4 is a struct -> rejected)
__device__ inline f32x4 ntload4(const float* p) {
  return __builtin_nontemporal_load((const f32x4*)p);
}

// ---------------- build A_g = [emb[x] | h] (64 x 2048) in bf16
__global__ __launch_bounds__(256) void k_cvtAg(const int* __restrict__ x,
    const float* __restrict__ h, const float* __restrict__ emb,
    __bf16* __restrict__ Ag) {
  int t = blockIdx.x * 256 + threadIdx.x;  // 0..131071
  int b = t >> 11, k = t & 2047;
  float v = (k < NE) ? emb[(size_t)x[b] * NE + k] : h[b * NH + (k - NE)];
  Ag[t] = (__bf16)v;
}

// ---------------- gates GEMM via bf16 MFMA (W streamed, no LDS staging)
__global__ __launch_bounds__(256) void k_gates_mfma(const __bf16* __restrict__ Ag,
    const float* __restrict__ Wih, const float* __restrict__ bih,
    const float* __restrict__ Whh, const float* __restrict__ bhh,
    float* __restrict__ gates) {
  __shared__ f32x4 red[4][4][64];
  int lane = threadIdx.x & 63;
  int wave = threadIdx.x >> 6;
  int col  = lane & 15;
  int grp  = lane >> 4;
  int j    = blockIdx.x * 16 + col;

  const float* Wsel = (wave < 2) ? Wih : Whh;
  const float*  wp  = Wsel + (size_t)j * 1024 + (wave & 1) * 512 + grp * 8;
  const __bf16* ap  = Ag + wave * 512 + grp * 8;

  f32x4 acc[4] = {};
#pragma unroll 4
  for (int ks = 0; ks < 16; ++ks) {
    int kb = ks * 32;
    f32x4 b0 = ntload4(wp + kb);
    f32x4 b1 = ntload4(wp + kb + 4);
    bf16_8 bf;
    bf[0] = (__bf16)b0[0]; bf[1] = (__bf16)b0[1];
    bf[2] = (__bf16)b0[2]; bf[3] = (__bf16)b0[3];
    bf[4] = (__bf16)b1[0]; bf[5] = (__bf16)b1[1];
    bf[6] = (__bf16)b1[2]; bf[7] = (__bf16)b1[3];
#pragma unroll
    for (int m = 0; m < 4; ++m) {
      bf16_8 a = *(const bf16_8*)(ap + (m * 16 + col) * NK2 + kb);
      acc[m] = __builtin_amdgcn_mfma_f32_16x16x32_bf16(a, bf, acc[m], 0, 0, 0);
    }
  }
#pragma unroll
  for (int m = 0; m < 4; ++m) red[wave][m][lane] = acc[m];
  __syncthreads();
  f32x4 s = red[0][wave][lane];
#pragma unroll
  for (int wv = 1; wv < 4; ++wv) s += red[wv][wave][lane];
  float bias = bih[j] + bhh[j];
  int b = wave * 16 + grp * 4;
#pragma unroll
  for (int r = 0; r < 4; ++r)
    gates[(b + r) * 4096 + j] = s[r] + bias;
}

// ---------------- LSTM cell elementwise (also emits bf16 h_new into A[:,1024:])
__global__ __launch_bounds__(256) void k_lstm(const float* __restrict__ gates,
    const float* __restrict__ c, float* __restrict__ hc_out,
    __bf16* __restrict__ A_bf) {
  int t = blockIdx.x * 256 + threadIdx.x;  // 0..NB*NH
  int b = t >> 10, hh = t & 1023;
  float ig = gates[b * 4096 + hh];
  float fg = gates[b * 4096 + 1024 + hh];
  float gg = gates[b * 4096 + 2048 + hh];
  float og = gates[b * 4096 + 3072 + hh];
  float i_ = 1.f / (1.f + expf(-ig));
  float f_ = 1.f / (1.f + expf(-fg));
  float g_ = tanhf(gg);
  float o_ = 1.f / (1.f + expf(-og));
  float cn = f_ * c[t] + i_ * g_;
  float hn = o_ * tanhf(cn);
  hc_out[t] = hn;                 // h_new
  hc_out[NB * NH + t] = cn;       // c_new
  A_bf[b * NK2 + 1024 + hh] = (__bf16)hn;
}

// ---------------- t = h_new @ W_bilin
__global__ __launch_bounds__(256) void k_bilin(const float* __restrict__ hnew,
    const float* __restrict__ Wb, float* __restrict__ t_out) {
  int b = blockIdx.x >> 2;
  int k = ((blockIdx.x & 3) << 8) + threadIdx.x;
  const float* hb = hnew + b * NH;
  float acc = 0.f;
#pragma unroll 8
  for (int hh = 0; hh < NH; ++hh)
    acc += hb[hh] * Wb[hh * NH + k];
  t_out[b * NH + k] = acc;
}

// ---------------- barrier-free flash attention: one WAVE per (b, 16-row strip).
// Per row: enc row in regs (4x f32x4/lane, nontemporal - zero reuse), dot vs
// reg-resident t, butterfly reduce, weighted context accumulate. No LDS/barriers.
// Masked rows (s>=len) get value 0 (not -inf) and DO accumulate, per reference.
__global__ __launch_bounds__(256) void k_attn(const float* __restrict__ t_in,
    const float* __restrict__ enc, const int* __restrict__ length,
    float* __restrict__ ctxp, float* __restrict__ ml) {
  int b     = blockIdx.x >> 4;                                   // 64
  int strip = ((blockIdx.x & 15) << 2) + (threadIdx.x >> 6);     // 0..63
  int lane  = threadIdx.x & 63;
  int len   = length[b];
  int s0    = strip * 16;

  const float* tp = t_in + b * NH;
  f32x4 tv[4];
#pragma unroll
  for (int i = 0; i < 4; ++i) tv[i] = *(const f32x4*)(tp + (i * 64 + lane) * 4);

  const float* ep = enc + ((size_t)b * NS + s0) * NH;

  float m_run = -1e30f, l_run = 0.f;
  f32x4 acc[4] = {};

#pragma unroll 2
  for (int r = 0; r < 16; ++r) {
    f32x4 e[4];
#pragma unroll
    for (int i = 0; i < 4; ++i) e[i] = ntload4(ep + (r * 256 + i * 64 + lane) * 4);
    float d = 0.f;
#pragma unroll
    for (int i = 0; i < 4; ++i)
      d += tv[i][0] * e[i][0] + tv[i][1] * e[i][1] + tv[i][2] * e[i][2] + tv[i][3] * e[i][3];
#pragma unroll
    for (int off = 32; off; off >>= 1) d += __shfl_xor(d, off);
    float v = (s0 + r < len) ? d : 0.f;
    float m_new = fmaxf(m_run, v);
    float f = expf(m_run - m_new);     // first iter: expf(-inf)=0, clean
    float w = expf(v - m_new);
    l_run = l_run * f + w;
#pragma unroll
    for (int i = 0; i < 4; ++i)
      acc[i] = acc[i] * f + w * e[i];
    m_run = m_new;
  }

  int idx = b * 64 + strip;
  float* P = ctxp + (size_t)idx * 1024;
#pragma unroll
  for (int i = 0; i < 4; ++i)
    *(f32x4*)(P + (i * 64 + lane) * 4) = acc[i];
  if (lane == 0) {
    ml[idx * 2]     = m_run;
    ml[idx * 2 + 1] = l_run;
  }
}

// ---------------- combine 64 strip partials -> context, emit bf16 into A[:,0:1024]
__global__ __launch_bounds__(256) void k_attn_combine(const float* __restrict__ ctxp,
    const float* __restrict__ ml, __bf16* __restrict__ A_bf) {
  int b = blockIdx.x;
  int tid = threadIdx.x;
  float M = -1e30f;
#pragma unroll
  for (int c = 0; c < 64; ++c) M = fmaxf(M, ml[(b * 64 + c) * 2]);
  float Z = 0.f;
  f32x4 num = {0.f, 0.f, 0.f, 0.f};
#pragma unroll 4
  for (int c = 0; c < 64; ++c) {
    float e = expf(ml[(b * 64 + c) * 2] - M);
    Z += e * ml[(b * 64 + c) * 2 + 1];
    f32x4 p = *(const f32x4*)(ctxp + ((size_t)(b * 64 + c)) * 1024 + tid * 4);
    num += e * p;
  }
  float inv = 1.f / Z;
  __bf16* dst = A_bf + b * NK2 + tid * 4;
#pragma unroll
  for (int i = 0; i < 4; ++i) dst[i] = (__bf16)(num[i] * inv);
}

// ---------------- out = A @ W_out^T + b_out via bf16 MFMA; one wave per block,
// 32 v-cols per wave. W streamed nontemporal (zero reuse); A cached (hot).
__global__ __launch_bounds__(64) void k_out_mfma(const __bf16* __restrict__ A,
    const float* __restrict__ Wout, const float* __restrict__ bout,
    float* __restrict__ out) {
  int lane = threadIdx.x;
  int col  = lane & 15;
  int grp  = lane >> 4;
  int vb   = blockIdx.x * 32;
  int va   = vb + col;
  int vc   = vb + 16 + col;
  int vaC  = va < NV ? va : NV - 1;
  int vcC  = vc < NV ? vc : NV - 1;

  const float*  wpA = Wout + (size_t)vaC * NK2 + grp * 8;
  const float*  wpB = Wout + (size_t)vcC * NK2 + grp * 8;
  const __bf16* ap  = A + grp * 8;

  f32x4 acc[4][2] = {};

#pragma unroll 2
  for (int ks = 0; ks < 64; ++ks) {
    int kb = ks * 32;
    f32x4 a0 = ntload4(wpA + kb);
    f32x4 a1 = ntload4(wpA + kb + 4);
    f32x4 c0 = ntload4(wpB + kb);
    f32x4 c1 = ntload4(wpB + kb + 4);
    bf16_8 bfA, bfB;
    bfA[0] = (__bf16)a0[0]; bfA[1] = (__bf16)a0[1];
    bfA[2] = (__bf16)a0[2]; bfA[3] = (__bf16)a0[3];
    bfA[4] = (__bf16)a1[0]; bfA[5] = (__bf16)a1[1];
    bfA[6] = (__bf16)a1[2]; bfA[7] = (__bf16)a1[3];
    bfB[0] = (__bf16)c0[0]; bfB[1] = (__bf16)c0[1];
    bfB[2] = (__bf16)c0[2]; bfB[3] = (__bf16)c0[3];
    bfB[4] = (__bf16)c1[0]; bfB[5] = (__bf16)c1[1];
    bfB[6] = (__bf16)c1[2]; bfB[7] = (__bf16)c1[3];
#pragma unroll
    for (int m = 0; m < 4; ++m) {
      bf16_8 a = *(const bf16_8*)(ap + (size_t)(m * 16 + col) * NK2 + kb);
      acc[m][0] = __builtin_amdgcn_mfma_f32_16x16x32_bf16(a, bfA, acc[m][0], 0, 0, 0);
      acc[m][1] = __builtin_amdgcn_mfma_f32_16x16x32_bf16(a, bfB, acc[m][1], 0, 0, 0);
    }
  }

#pragma unroll
  for (int n = 0; n < 2; ++n) {
    int vrow = vb + n * 16 + col;
    if (vrow < NV) {
      float bb = bout[vrow];
      int mrow = grp * 4;
#pragma unroll
      for (int m = 0; m < 4; ++m)
#pragma unroll
        for (int r = 0; r < 4; ++r)
          out[(size_t)(m * 16 + mrow + r) * NV + vrow] = acc[m][n][r] + bb;
    }
  }
}

extern "C" void kernel_launch(void* const* d_in, const int* in_sizes, int n_in,
                              void* d_out, int out_size, void* d_ws, size_t ws_size,
                              hipStream_t stream) {
  const int*   x      = (const int*)d_in[0];
  const float* h      = (const float*)d_in[1];
  const float* c      = (const float*)d_in[2];
  const float* enc    = (const float*)d_in[3];
  const int*   length = (const int*)d_in[4];
  const float* emb    = (const float*)d_in[5];
  const float* Wih    = (const float*)d_in[6];
  const float* bih    = (const float*)d_in[7];
  const float* Whh    = (const float*)d_in[8];
  const float* bhh    = (const float*)d_in[9];
  const float* Wb     = (const float*)d_in[10];
  const float* Wout   = (const float*)d_in[11];
  const float* bout   = (const float*)d_in[12];

  float* out = (float*)d_out;
  float* hn  = out + (size_t)NB * NV;          // h_new region of d_out
  // c_new region = hn + NB*NH (written by k_lstm)

  float* ws      = (float*)d_ws;
  float* gates   = ws;                              // NB*4H f32
  float* t_ws    = gates + NB * 4 * NH;             // NB*NH f32
  float* ctxp    = t_ws + NB * NH;                  // 64*NB*1024 f32 (16MB)
  float* ml      = ctxp + 64 * (size_t)NB * 1024;   // NB*64*2 f32
  __bf16* A_bf   = (__bf16*)(ml + NB * 128);        // NB*NK2 bf16
  __bf16* Ag_bf  = A_bf + NB * NK2;                 // NB*NK2 bf16

  k_cvtAg<<<NB * NK2 / 256, 256, 0, stream>>>(x, h, emb, Ag_bf);
  k_gates_mfma<<<4096 / 16, 256, 0, stream>>>(Ag_bf, Wih, bih, Whh, bhh, gates);
  k_lstm<<<NB * NH / 256, 256, 0, stream>>>(gates, c, hn, A_bf);
  k_bilin<<<NB * 4, 256, 0, stream>>>(hn, Wb, t_ws);
  k_attn<<<NB * 16, 256, 0, stream>>>(t_ws, enc, length, ctxp, ml);
  k_attn_combine<<<NB, 256, 0, stream>>>(ctxp, ml, A_bf);
  k_out_mfma<<<(NV + 31) / 32, 64, 0, stream>>>(A_bf, Wout, bout, out);
}